// Round 18
// baseline (205.506 us; speedup 1.0000x reference)
//
#include <hip/hip_runtime.h>
#include <math.h>

#define B_DIM 2048
#define M_DIM 4096
#define N_DIM 64
#define S_DIM 64
#define EPS_TOTAL 0.001f
#define MSPLIT 32
#define MR (M_DIM / MSPLIT)  // 128 m per block
#define BTILE 64             // b per block

typedef __attribute__((ext_vector_type(8))) short short8v;
typedef __attribute__((ext_vector_type(4))) short short4v;
typedef __attribute__((ext_vector_type(4))) float float4v;
typedef __attribute__((ext_vector_type(2))) float float2v;

#define MFMA(a, b, c) __builtin_amdgcn_mfma_f32_16x16x32_bf16(a, b, c, 0, 0, 0)

// Module-owned buffers.
// wfrag: [mtile 256][ks 4][mat 2 (W1=dj, W3=zj)][split 2][lane 64][8] (4.2MB)
__device__ unsigned short wfrag_g[256 * 4 * 2 * 2 * 64 * 8];
// tfrag: [mchunk 64][ct 4][ks2 2][split 2][lane 64][8 bf16]  (1 MB)
__device__ unsigned short tfrag_g[64 * 4 * 2 * 2 * 64 * 8];
// afrag: [bw 128][ks 4][arr 4 (A1h,A1l,A2h,A2l)][lane 64][8 bf16]  (2 MB)
__device__ unsigned short afrag_g[128 * 4 * 4 * 64 * 8];
// mc: [m][8] = c1r, c1i, zj2, Km, A2, B2, nsoL, nspmoL  (quad-poly consts)
__device__ __align__(16) float mc_g[M_DIM * 8];
__device__ float bsq_g[B_DIM * 2];   // z2, dsq
__device__ float part_g[(size_t)MSPLIT * B_DIM * S_DIM];  // 16.8 MB
__device__ unsigned int red_cnt[32];  // per-bt arrival counters

__device__ inline unsigned short f32_bf16(float x) {
  unsigned int u = __float_as_uint(x);
  unsigned int r = (u + 0x7fffu + ((u >> 16) & 1u)) >> 16;  // RNE
  return (unsigned short)r;
}
__device__ inline float bf16_f32(unsigned short h) {
  return __uint_as_float(((unsigned int)h) << 16);
}
__device__ inline float fast_exp2(float x) {
#if __has_builtin(__builtin_amdgcn_exp2f)
  return __builtin_amdgcn_exp2f(x);
#else
  float r;
  asm("v_exp_f32 %0, %1" : "=v"(r) : "v"(x));
  return r;
#endif
}
__device__ inline void stage16(const unsigned short* src,
                               unsigned short* dst) {
  __builtin_amdgcn_global_load_lds(
      (const __attribute__((address_space(1))) void*)src,
      (__attribute__((address_space(3))) void*)dst, 16, 0, 0);
}

// ------------- P1 (merged): fragments + per-m consts + per-b norms -------
// blocks [0,512): wfrag (vectorized, fused hi/lo); [512,640): tfrag (fused);
// [640,768): afrag; [768,1792): mconst; [1792,2304): bsq.
__global__ __launch_bounds__(256) void build_all(
    const float* __restrict__ zj_re, const float* __restrict__ zj_im,
    const float* __restrict__ dj_re, const float* __restrict__ dj_im,
    const float* __restrict__ That_re,
    const float* __restrict__ alpha, const float* __restrict__ sig_par,
    const float* __restrict__ sig_perp,
    const float* __restrict__ z_re, const float* __restrict__ z_im,
    const float* __restrict__ d_re, const float* __restrict__ d_im) {
  if (blockIdx.x < 512) {  // ---- wfrag: float4 loads, both splits ----
    if (blockIdx.x == 0 && threadIdx.x < 32) red_cnt[threadIdx.x] = 0;
    const int gid = blockIdx.x * 256 + threadIdx.x;  // [0, 131072)
    const int lane = gid & 63;
    const int rest = gid >> 6;  // [mtile 256][ks 4][mat 2]
    const int mat = rest & 1;   // 0 = W1 (dj), 1 = W3 (zj)
    const int ks = (rest >> 1) & 3;
    const int mtile = rest >> 3;
    const int m = mtile * 16 + (lane & 15);
    const int g = lane >> 4;
    unsigned short oh[8], ol[8];
#pragma unroll
    for (int h = 0; h < 2; ++h) {
      const int C = ks * 32 + h * 16;  // k<64 uniform per (ks,h)
      const float* base = (C < 64) ? (mat ? zj_re : dj_re)
                                   : (mat ? zj_im : dj_im);
      const float4 v = *(const float4*)(base + m * 64 + (C & 63) + g * 4);
      const float av[4] = {v.x, v.y, v.z, v.w};
#pragma unroll
      for (int e2 = 0; e2 < 4; ++e2) {
        const int e = h * 4 + e2;
        const unsigned short hi = f32_bf16(av[e2]);
        oh[e] = hi;
        ol[e] = f32_bf16(av[e2] - bf16_f32(hi));
      }
    }
    const size_t idx =
        ((((size_t)(mtile * 4 + ks) * 2 + mat) * 2) * 64 + lane) * 8;
    uint4 u;
    u.x = (unsigned)oh[0] | ((unsigned)oh[1] << 16);
    u.y = (unsigned)oh[2] | ((unsigned)oh[3] << 16);
    u.z = (unsigned)oh[4] | ((unsigned)oh[5] << 16);
    u.w = (unsigned)oh[6] | ((unsigned)oh[7] << 16);
    *(uint4*)(wfrag_g + idx) = u;
    u.x = (unsigned)ol[0] | ((unsigned)ol[1] << 16);
    u.y = (unsigned)ol[2] | ((unsigned)ol[3] << 16);
    u.z = (unsigned)ol[4] | ((unsigned)ol[5] << 16);
    u.w = (unsigned)ol[6] | ((unsigned)ol[7] << 16);
    *(uint4*)(wfrag_g + idx + 512) = u;  // split stride = 512 shorts
  } else if (blockIdx.x < 640) {  // ---- tfrag (fused hi/lo) ----
    const int gid2 = (blockIdx.x - 512) * 256 + threadIdx.x;  // [0, 32768)
    const int lane = gid2 & 63;
    const int rest = gid2 >> 6;  // [mchunk 64][ct 4][ks2 2]
    const int ks2 = rest & 1;
    const int ct = (rest >> 1) & 3;
    const int mchunk = rest >> 3;
    const int s = ct * 16 + (lane & 15);
    const int g = lane >> 4;
    unsigned short oh[8], ol[8];
#pragma unroll
    for (int e = 0; e < 8; ++e) {
      const int k = ks2 * 32 + ((e >> 2) << 4) + (g << 2) + (e & 3);
      const float v = That_re[(size_t)(mchunk * 64 + k) * S_DIM + s];
      const unsigned short hi = f32_bf16(v);
      oh[e] = hi;
      ol[e] = f32_bf16(v - bf16_f32(hi));
    }
    const size_t idx =
        ((((size_t)(mchunk * 4 + ct) * 2 + ks2) * 2) * 64 + lane) * 8;
    uint4 u;
    u.x = (unsigned)oh[0] | ((unsigned)oh[1] << 16);
    u.y = (unsigned)oh[2] | ((unsigned)oh[3] << 16);
    u.z = (unsigned)oh[4] | ((unsigned)oh[5] << 16);
    u.w = (unsigned)oh[6] | ((unsigned)oh[7] << 16);
    *(uint4*)(tfrag_g + idx) = u;
    u.x = (unsigned)ol[0] | ((unsigned)ol[1] << 16);
    u.y = (unsigned)ol[2] | ((unsigned)ol[3] << 16);
    u.z = (unsigned)ol[4] | ((unsigned)ol[5] << 16);
    u.w = (unsigned)ol[6] | ((unsigned)ol[7] << 16);
    *(uint4*)(tfrag_g + idx + 512) = u;
  } else if (blockIdx.x < 768) {  // ---- afrag (cheap float4 build) ----
    const int gid2 = (blockIdx.x - 640) * 256 + threadIdx.x;  // [0,32768)
    const int lane = gid2 & 63;
    const int rest = gid2 >> 6;  // [bw 128][ks 4]
    const int ks = rest & 3;
    const int bw = rest >> 2;
    const int bb = bw * 16 + (lane & 15);
    const int g = lane >> 4;
    unsigned short o[4][8];  // arr = A1h, A1l, A2h, A2l
#pragma unroll
    for (int h = 0; h < 2; ++h) {
      const int C = ks * 32 + h * 16;
      const float* p1 =
          (C < 64) ? (z_re + bb * 64 + C) : (z_im + bb * 64 + C - 64);
      const float* p2 =
          (C < 64) ? (d_re + bb * 64 + C) : (d_im + bb * 64 + C - 64);
      const float4 vz = *(const float4*)(p1 + g * 4);
      const float4 vd = *(const float4*)(p2 + g * 4);
      const float az[4] = {vz.x, vz.y, vz.z, vz.w};
      const float ad[4] = {vd.x, vd.y, vd.z, vd.w};
#pragma unroll
      for (int e2 = 0; e2 < 4; ++e2) {
        const int e = h * 4 + e2;
        const unsigned short h1 = f32_bf16(az[e2]);
        o[0][e] = h1;
        o[1][e] = f32_bf16(az[e2] - bf16_f32(h1));
        const unsigned short h2 = f32_bf16(ad[e2]);
        o[2][e] = h2;
        o[3][e] = f32_bf16(ad[e2] - bf16_f32(h2));
      }
    }
#pragma unroll
    for (int arr = 0; arr < 4; ++arr) {
      uint4 u;
      u.x = (unsigned)o[arr][0] | ((unsigned)o[arr][1] << 16);
      u.y = (unsigned)o[arr][2] | ((unsigned)o[arr][3] << 16);
      u.z = (unsigned)o[arr][4] | ((unsigned)o[arr][5] << 16);
      u.w = (unsigned)o[arr][6] | ((unsigned)o[arr][7] << 16);
      *(uint4*)(afrag_g +
                (((size_t)(bw * 4 + ks) * 4 + arr) * 64 + lane) * 8) = u;
    }
  } else if (blockIdx.x < 768 + M_DIM / 4) {  // ---- mconst ----
    const int w = threadIdx.x >> 6, lane = threadIdx.x & 63;
    const int m = (blockIdx.x - 768) * 4 + w;
    const int idx = m * N_DIM + lane;
    const float djr = dj_re[idx], dji = dj_im[idx];
    const float zjr = zj_re[idx], zji = zj_im[idx];
    float dd2 = djr * djr + dji * dji;
    float c1r = djr * zjr + dji * zji;
    float c1i = djr * zji - dji * zjr;
    float zj2 = zjr * zjr + zji * zji;
#pragma unroll
    for (int off = 1; off < 64; off <<= 1) {
      dd2 += __shfl_xor(dd2, off);
      c1r += __shfl_xor(c1r, off);
      c1i += __shfl_xor(c1i, off);
      zj2 += __shfl_xor(zj2, off);
    }
    if (lane == 0) {
      const float L = 1.4426950408889634f;
      const float sp = sig_par[m], so = sig_perp[m];
      const float nsp = -0.5f / fmaf(sp, sp, EPS_TOTAL);
      const float nso = -0.5f / fmaf(so, so, EPS_TOTAL);
      const float nsoL = nso * L;
      const float nspmoL = (nsp - nso) * L;
      const float t = nspmoL * dd2 + nsoL;
      float* o = mc_g + m * 8;
      o[0] = c1r;
      o[1] = c1i;
      o[2] = zj2;
      o[3] = dd2 * nsoL + log2f(alpha[m]);  // Km
      o[4] = dd2 * t;                        // A2
      o[5] = -2.f * t;                       // B2
      o[6] = nsoL;
      o[7] = nspmoL;
    }
  } else {  // ---- bsq ----
    const int w = threadIdx.x >> 6, lane = threadIdx.x & 63;
    const int b = (blockIdx.x - 768 - M_DIM / 4) * 4 + w;
    const int idx = b * N_DIM + lane;
    const float zr = z_re[idx], zi = z_im[idx];
    const float dr = d_re[idx], di = d_im[idx];
    float z2 = zr * zr + zi * zi;
    float dsq = dr * dr + di * di;
#pragma unroll
    for (int off = 1; off < 64; off <<= 1) {
      z2 += __shfl_xor(z2, off);
      dsq += __shfl_xor(dsq, off);
    }
    if (lane == 0) {
      bsq_g[b * 2] = z2;
      bsq_g[b * 2 + 1] = dsq;
    }
  }
}

// ------------- main: r15 structure verbatim + fused last-block reduce ----
__global__ __launch_bounds__(256) void cpsf_mfma(float* __restrict__ out) {
  __shared__ __align__(16) unsigned short wbuf[8192];
  __shared__ __align__(16) unsigned short wgt_hi[64][68];
  __shared__ int is_last;

  const int tid = threadIdx.x;
  const int w = tid >> 6, lane = tid & 63;
  // XCD-aware swizzle over the full 1024-block grid.
  const int q = blockIdx.x >> 3, x = blockIdx.x & 7;
  const int ms = x + 8 * (q & 3);   // [0,32)
  const int bt = q >> 2;            // [0,32)
  const int b0 = bt * BTILE;
  const int g = lane >> 4;

  // ---- A fragments: prebuilt, coalesced lane*16B loads ----
  const int bw = bt * 4 + w;
  short8v A1h[4], A1l[4], A2h[4], A2l[4];
#pragma unroll
  for (int ks = 0; ks < 4; ++ks) {
    const unsigned short* ap =
        afrag_g + (((size_t)(bw * 4 + ks) * 4) * 64 + lane) * 8;
    A1h[ks] = *(const short8v*)(ap + 0 * 512);
    A1l[ks] = *(const short8v*)(ap + 1 * 512);
    A2h[ks] = *(const short8v*)(ap + 2 * 512);
    A2l[ks] = *(const short8v*)(ap + 3 * 512);
  }

  // per-b squared norms for this thread's 4 output rows (constant over m)
  float bz[4], bd[4];
#pragma unroll
  for (int r = 0; r < 4; ++r) {
    const int bloc = b0 + w * 16 + g * 4 + r;
    bz[r] = bsq_g[bloc * 2];
    bd[r] = bsq_g[bloc * 2 + 1];
  }

  const float2v TQ2[4] = {{0.019855071751231885f, 0.101666761293186630f},
                          {0.237233795041835510f, 0.408282678752175100f},
                          {0.591717321247824900f, 0.762766204958164500f},
                          {0.898333238706813370f, 0.980144928248768120f}};
  const float2v WQ2[4] = {{0.050614268145188130f, 0.111190517226687240f},
                          {0.156853322938943640f, 0.181341891689180990f},
                          {0.181341891689180990f, 0.156853322938943640f},
                          {0.111190517226687240f, 0.050614268145188130f}};

  float4v Tacc[4];
#pragma unroll
  for (int i = 0; i < 4; ++i) Tacc[i] = (float4v){0.f, 0.f, 0.f, 0.f};

#pragma unroll
  for (int ci = 0; ci < MR / 64; ++ci) {
    const int m0 = ms * MR + ci * 64;
    const int mtile0 = m0 >> 4;

#pragma unroll
    for (int mt = 0; mt < 4; ++mt) {
      // ---- stage this (ci,mt)'s wfrag chunk (16 KB) into LDS ----
      __syncthreads();  // all waves done reading wbuf from previous phase
      {
        const unsigned short* src =
            wfrag_g + ((size_t)((mtile0 + mt) * 4 + w)) * 2048 + lane * 8;
#pragma unroll
        for (int j = 0; j < 4; ++j)
          stage16(src + j * 512, &wbuf[(w * 4 + j) * 512]);
      }
      __syncthreads();  // staged data visible (vmcnt drained)

      // ---- K=128 GEMM from LDS ----
      // ipr, ipiP (z_im*dj_re), ipiN (z_re*dj_im), zd, ad
      float4v acc0 = {0.f, 0.f, 0.f, 0.f}, accP = acc0, accN = acc0,
              acc2 = acc0, acc3 = acc0;
#pragma unroll
      for (int ks = 0; ks < 4; ++ks) {
        const unsigned short* wp = &wbuf[(ks * 4) * 512 + lane * 8];
        const short8v w1h = *(const short8v*)(wp + 0 * 512);
        const short8v w1l = *(const short8v*)(wp + 1 * 512);
        const short8v w3h = *(const short8v*)(wp + 2 * 512);
        const short8v w3l = *(const short8v*)(wp + 3 * 512);
        const short8v a1h = A1h[ks], a1l = A1l[ks];
        // ipi trick: W2 = [-dj_im; dj_re] = k-slice-swapped W1 with one
        // half negated -> accumulate A1[ks^2] x W1[ks] into accP/accN.
        const short8v s1h = A1h[ks ^ 2], s1l = A1l[ks ^ 2];
        const short8v a2h = A2h[ks], a2l = A2l[ks];
        acc0 = MFMA(a1h, w1h, acc0);
        acc0 = MFMA(a1h, w1l, acc0);
        acc0 = MFMA(a1l, w1h, acc0);
        if (ks < 2) {
          accP = MFMA(s1h, w1h, accP);
          accP = MFMA(s1h, w1l, accP);
          accP = MFMA(s1l, w1h, accP);
        } else {
          accN = MFMA(s1h, w1h, accN);
          accN = MFMA(s1h, w1l, accN);
          accN = MFMA(s1l, w1h, accN);
        }
        acc2 = MFMA(a1h, w3h, acc2);
        acc2 = MFMA(a1h, w3l, acc2);
        acc2 = MFMA(a1l, w3h, acc2);
        acc3 = MFMA(a2h, w1h, acc3);
        acc3 = MFMA(a2h, w1l, acc3);
        acc3 = MFMA(a2l, w1h, acc3);
      }

      // poly quadrature: arg(t) = A2 t^2 + B2 t + C, exp2, alpha folded.
      const int mloc = mt * 16 + (lane & 15);
      const float4 mA = *(const float4*)(mc_g + (size_t)(m0 + mloc) * 8);
      const float4 mB = *(const float4*)(mc_g + (size_t)(m0 + mloc) * 8 + 4);
      const float c1r = mA.x, c1i = mA.y, zj2 = mA.z, Km = mA.w;
      const float A2 = mB.x, B2 = mB.y, nsoL = mB.z, nspmoL = mB.w;
#pragma unroll
      for (int r = 0; r < 4; ++r) {
        const float ipr2 = acc0[r] - c1r;
        const float ipi2 = (accP[r] - accN[r]) - c1i;
        const float q0 = fmaf(-2.f, acc2[r], bz[r]) + zj2;
        const float db = fmaf(fmaf(-2.f, acc3[r], bd[r]), nsoL, Km);
        const float r2 = fmaf(ipr2, ipr2, ipi2 * ipi2);
        const float bq = ipr2 * B2;
        const float cc = fmaf(nspmoL, r2, fmaf(nsoL, q0, db));
        const float2v A2v = {A2, A2}, bqv = {bq, bq}, ccv = {cc, cc};
        float2v qa = {0.f, 0.f};
#pragma unroll
        for (int kp = 0; kp < 4; ++kp) {
          const float2v tk = TQ2[kp];
          const float2v arg = (A2v * tk + bqv) * tk + ccv;
          const float2v ex = {fast_exp2(arg.x), fast_exp2(arg.y)};
          qa += WQ2[kp] * ex;
        }
        const int bloc = w * 16 + g * 4 + r;
        wgt_hi[bloc][mloc] = f32_bf16(qa.x + qa.y);
      }
    }

    // ---- That accumulation via MFMA (wgt single-bf16 x tfrag hi/lo);
    // wave-private wgt rows -> in-wave LDS ordering, no barrier ----
    const int mchunk = ms * (MR / 64) + ci;
#pragma unroll
    for (int ks2 = 0; ks2 < 2; ++ks2) {
      const int row = w * 16 + (lane & 15);
      const int colb = ks2 * 32 + g * 4;
      const short4v p0 = *(const short4v*)&wgt_hi[row][colb];
      const short4v p1 = *(const short4v*)&wgt_hi[row][colb + 16];
      const short8v ah = __builtin_shufflevector(p0, p1, 0, 1, 2, 3, 4, 5, 6, 7);
#pragma unroll
      for (int ct = 0; ct < 4; ++ct) {
        const size_t toff =
            ((((size_t)mchunk * 4 + ct) * 2 + ks2) * 2) * 512 + lane * 8;
        const short8v th = *(const short8v*)(tfrag_g + toff);
        const short8v tl = *(const short8v*)(tfrag_g + toff + 512);
        Tacc[ct] = MFMA(ah, th, Tacc[ct]);
        Tacc[ct] = MFMA(ah, tl, Tacc[ct]);
      }
    }
  }

  // partial T for this m-split: D row = 4g + r, col = ct*16+(lane&15).
#pragma unroll
  for (int ct = 0; ct < 4; ++ct)
#pragma unroll
    for (int r = 0; r < 4; ++r)
      part_g[((size_t)ms * B_DIM + (b0 + w * 16 + g * 4 + r)) * S_DIM +
             ct * 16 + (lane & 15)] = Tacc[ct][r];

  // ---- fused last-block reduction for this bt (release/acquire) ----
  __threadfence();   // release: make this thread's partials visible
  __syncthreads();   // all threads' stores + fences done
  if (tid == 0)
    is_last = (atomicAdd(&red_cnt[bt], 1u) == MSPLIT - 1) ? 1 : 0;
  __syncthreads();
  if (is_last) {
    __threadfence();  // acquire: invalidate stale cache lines
    for (int i = tid; i < 64 * 16; i += 256) {
      const int bl = i >> 4, s4 = (i & 15) * 4;
      float4 s = {0.f, 0.f, 0.f, 0.f};
#pragma unroll 8
      for (int p = 0; p < MSPLIT; ++p) {  // fixed order: bit-identical
        const float4 v = *(const float4*)(
            part_g + ((size_t)p * B_DIM + b0 + bl) * S_DIM + s4);
        s.x += v.x;
        s.y += v.y;
        s.z += v.z;
        s.w += v.w;
      }
      *(float4*)(out + (size_t)(b0 + bl) * S_DIM + s4) = s;
    }
  }
}

extern "C" void kernel_launch(void* const* d_in, const int* in_sizes, int n_in,
                              void* d_out, int out_size, void* d_ws,
                              size_t ws_size, hipStream_t stream) {
  const float* z_re = (const float*)d_in[0];
  const float* z_im = (const float*)d_in[1];
  const float* d_re = (const float*)d_in[2];
  const float* d_im = (const float*)d_in[3];
  const float* zj_re = (const float*)d_in[4];
  const float* zj_im = (const float*)d_in[5];
  const float* dj_re = (const float*)d_in[6];
  const float* dj_im = (const float*)d_in[7];
  const float* That_re = (const float*)d_in[8];
  const float* alpha = (const float*)d_in[10];
  const float* sig_par = (const float*)d_in[11];
  const float* sig_perp = (const float*)d_in[12];

  build_all<<<dim3(768 + M_DIM / 4 + B_DIM / 4), dim3(256), 0, stream>>>(
      zj_re, zj_im, dj_re, dj_im, That_re, alpha, sig_par, sig_perp, z_re,
      z_im, d_re, d_im);
  cpsf_mfma<<<dim3((B_DIM / BTILE) * MSPLIT), dim3(256), 0, stream>>>(
      (float*)d_out);
}

// Round 19
// 51.396 us; speedup vs baseline: 3.9985x; 3.9985x over previous
//
#include <hip/hip_runtime.h>
#include <math.h>

#define B_DIM 2048
#define M_DIM 4096
#define N_DIM 64
#define S_DIM 64
#define EPS_TOTAL 0.001f
#define MSPLIT 32
#define MR (M_DIM / MSPLIT)  // 128 m per block
#define BTILE 64             // b per block

typedef __attribute__((ext_vector_type(8))) short short8v;
typedef __attribute__((ext_vector_type(4))) short short4v;
typedef __attribute__((ext_vector_type(4))) float float4v;
typedef __attribute__((ext_vector_type(2))) float float2v;

#define MFMA(a, b, c) __builtin_amdgcn_mfma_f32_16x16x32_bf16(a, b, c, 0, 0, 0)

// Module-owned buffers.
// wfrag: [mtile 256][ks 4][mat 2 (W1=dj, W3=zj)][split 2][lane 64][8] (4.2MB)
__device__ unsigned short wfrag_g[256 * 4 * 2 * 2 * 64 * 8];
// tfrag: [mchunk 64][ct 4][ks2 2][split 2][lane 64][8 bf16]  (1 MB)
__device__ unsigned short tfrag_g[64 * 4 * 2 * 2 * 64 * 8];
// afrag: [bw 128][ks 4][arr 4 (A1h,A1l,A2h,A2l)][lane 64][8 bf16]  (2 MB)
__device__ unsigned short afrag_g[128 * 4 * 4 * 64 * 8];
// mc: [m][8] = c1r, c1i, zj2, Km, A2, B2, nsoL, nspmoL  (quad-poly consts)
__device__ __align__(16) float mc_g[M_DIM * 8];
__device__ float bsq_g[B_DIM * 2];   // z2, dsq
__device__ float part_g[(size_t)MSPLIT * B_DIM * S_DIM];  // 16.8 MB

__device__ inline unsigned short f32_bf16(float x) {
  unsigned int u = __float_as_uint(x);
  unsigned int r = (u + 0x7fffu + ((u >> 16) & 1u)) >> 16;  // RNE
  return (unsigned short)r;
}
__device__ inline float bf16_f32(unsigned short h) {
  return __uint_as_float(((unsigned int)h) << 16);
}
__device__ inline float fast_exp2(float x) {
#if __has_builtin(__builtin_amdgcn_exp2f)
  return __builtin_amdgcn_exp2f(x);
#else
  float r;
  asm("v_exp_f32 %0, %1" : "=v"(r) : "v"(x));
  return r;
#endif
}
__device__ inline void stage16(const unsigned short* src,
                               unsigned short* dst) {
  __builtin_amdgcn_global_load_lds(
      (const __attribute__((address_space(1))) void*)src,
      (__attribute__((address_space(3))) void*)dst, 16, 0, 0);
}

// ------------- P1 (merged): fragments + per-m consts + per-b norms -------
// blocks [0,512): wfrag (vectorized, fused hi/lo); [512,640): tfrag (fused);
// [640,768): afrag; [768,1792): mconst; [1792,2304): bsq.
__global__ __launch_bounds__(256) void build_all(
    const float* __restrict__ zj_re, const float* __restrict__ zj_im,
    const float* __restrict__ dj_re, const float* __restrict__ dj_im,
    const float* __restrict__ That_re,
    const float* __restrict__ alpha, const float* __restrict__ sig_par,
    const float* __restrict__ sig_perp,
    const float* __restrict__ z_re, const float* __restrict__ z_im,
    const float* __restrict__ d_re, const float* __restrict__ d_im) {
  if (blockIdx.x < 512) {  // ---- wfrag: float4 loads, both splits ----
    const int gid = blockIdx.x * 256 + threadIdx.x;  // [0, 131072)
    const int lane = gid & 63;
    const int rest = gid >> 6;  // [mtile 256][ks 4][mat 2]
    const int mat = rest & 1;   // 0 = W1 (dj), 1 = W3 (zj)
    const int ks = (rest >> 1) & 3;
    const int mtile = rest >> 3;
    const int m = mtile * 16 + (lane & 15);
    const int g = lane >> 4;
    unsigned short oh[8], ol[8];
#pragma unroll
    for (int h = 0; h < 2; ++h) {
      const int C = ks * 32 + h * 16;  // k<64 uniform per (ks,h)
      const float* base = (C < 64) ? (mat ? zj_re : dj_re)
                                   : (mat ? zj_im : dj_im);
      const float4 v = *(const float4*)(base + m * 64 + (C & 63) + g * 4);
      const float av[4] = {v.x, v.y, v.z, v.w};
#pragma unroll
      for (int e2 = 0; e2 < 4; ++e2) {
        const int e = h * 4 + e2;
        const unsigned short hi = f32_bf16(av[e2]);
        oh[e] = hi;
        ol[e] = f32_bf16(av[e2] - bf16_f32(hi));
      }
    }
    // layout-identical to r15: [mtile][ks][mat][split][lane][8]
    const size_t idx =
        ((((size_t)(mtile * 4 + ks) * 2 + mat) * 2) * 64 + lane) * 8;
    uint4 u;
    u.x = (unsigned)oh[0] | ((unsigned)oh[1] << 16);
    u.y = (unsigned)oh[2] | ((unsigned)oh[3] << 16);
    u.z = (unsigned)oh[4] | ((unsigned)oh[5] << 16);
    u.w = (unsigned)oh[6] | ((unsigned)oh[7] << 16);
    *(uint4*)(wfrag_g + idx) = u;
    u.x = (unsigned)ol[0] | ((unsigned)ol[1] << 16);
    u.y = (unsigned)ol[2] | ((unsigned)ol[3] << 16);
    u.z = (unsigned)ol[4] | ((unsigned)ol[5] << 16);
    u.w = (unsigned)ol[6] | ((unsigned)ol[7] << 16);
    *(uint4*)(wfrag_g + idx + 512) = u;  // split stride = 512 shorts
  } else if (blockIdx.x < 640) {  // ---- tfrag (fused hi/lo) ----
    const int gid2 = (blockIdx.x - 512) * 256 + threadIdx.x;  // [0, 32768)
    const int lane = gid2 & 63;
    const int rest = gid2 >> 6;  // [mchunk 64][ct 4][ks2 2]
    const int ks2 = rest & 1;
    const int ct = (rest >> 1) & 3;
    const int mchunk = rest >> 3;
    const int s = ct * 16 + (lane & 15);
    const int g = lane >> 4;
    unsigned short oh[8], ol[8];
#pragma unroll
    for (int e = 0; e < 8; ++e) {
      const int k = ks2 * 32 + ((e >> 2) << 4) + (g << 2) + (e & 3);
      const float v = That_re[(size_t)(mchunk * 64 + k) * S_DIM + s];
      const unsigned short hi = f32_bf16(v);
      oh[e] = hi;
      ol[e] = f32_bf16(v - bf16_f32(hi));
    }
    const size_t idx =
        ((((size_t)(mchunk * 4 + ct) * 2 + ks2) * 2) * 64 + lane) * 8;
    uint4 u;
    u.x = (unsigned)oh[0] | ((unsigned)oh[1] << 16);
    u.y = (unsigned)oh[2] | ((unsigned)oh[3] << 16);
    u.z = (unsigned)oh[4] | ((unsigned)oh[5] << 16);
    u.w = (unsigned)oh[6] | ((unsigned)oh[7] << 16);
    *(uint4*)(tfrag_g + idx) = u;
    u.x = (unsigned)ol[0] | ((unsigned)ol[1] << 16);
    u.y = (unsigned)ol[2] | ((unsigned)ol[3] << 16);
    u.z = (unsigned)ol[4] | ((unsigned)ol[5] << 16);
    u.w = (unsigned)ol[6] | ((unsigned)ol[7] << 16);
    *(uint4*)(tfrag_g + idx + 512) = u;
  } else if (blockIdx.x < 768) {  // ---- afrag (cheap float4 build) ----
    const int gid2 = (blockIdx.x - 640) * 256 + threadIdx.x;  // [0,32768)
    const int lane = gid2 & 63;
    const int rest = gid2 >> 6;  // [bw 128][ks 4]
    const int ks = rest & 3;
    const int bw = rest >> 2;
    const int bb = bw * 16 + (lane & 15);
    const int g = lane >> 4;
    unsigned short o[4][8];  // arr = A1h, A1l, A2h, A2l
#pragma unroll
    for (int h = 0; h < 2; ++h) {
      const int C = ks * 32 + h * 16;
      const float* p1 =
          (C < 64) ? (z_re + bb * 64 + C) : (z_im + bb * 64 + C - 64);
      const float* p2 =
          (C < 64) ? (d_re + bb * 64 + C) : (d_im + bb * 64 + C - 64);
      const float4 vz = *(const float4*)(p1 + g * 4);
      const float4 vd = *(const float4*)(p2 + g * 4);
      const float az[4] = {vz.x, vz.y, vz.z, vz.w};
      const float ad[4] = {vd.x, vd.y, vd.z, vd.w};
#pragma unroll
      for (int e2 = 0; e2 < 4; ++e2) {
        const int e = h * 4 + e2;
        const unsigned short h1 = f32_bf16(az[e2]);
        o[0][e] = h1;
        o[1][e] = f32_bf16(az[e2] - bf16_f32(h1));
        const unsigned short h2 = f32_bf16(ad[e2]);
        o[2][e] = h2;
        o[3][e] = f32_bf16(ad[e2] - bf16_f32(h2));
      }
    }
#pragma unroll
    for (int arr = 0; arr < 4; ++arr) {
      uint4 u;
      u.x = (unsigned)o[arr][0] | ((unsigned)o[arr][1] << 16);
      u.y = (unsigned)o[arr][2] | ((unsigned)o[arr][3] << 16);
      u.z = (unsigned)o[arr][4] | ((unsigned)o[arr][5] << 16);
      u.w = (unsigned)o[arr][6] | ((unsigned)o[arr][7] << 16);
      *(uint4*)(afrag_g +
                (((size_t)(bw * 4 + ks) * 4 + arr) * 64 + lane) * 8) = u;
    }
  } else if (blockIdx.x < 768 + M_DIM / 4) {  // ---- mconst ----
    const int w = threadIdx.x >> 6, lane = threadIdx.x & 63;
    const int m = (blockIdx.x - 768) * 4 + w;
    const int idx = m * N_DIM + lane;
    const float djr = dj_re[idx], dji = dj_im[idx];
    const float zjr = zj_re[idx], zji = zj_im[idx];
    float dd2 = djr * djr + dji * dji;
    float c1r = djr * zjr + dji * zji;
    float c1i = djr * zji - dji * zjr;
    float zj2 = zjr * zjr + zji * zji;
#pragma unroll
    for (int off = 1; off < 64; off <<= 1) {
      dd2 += __shfl_xor(dd2, off);
      c1r += __shfl_xor(c1r, off);
      c1i += __shfl_xor(c1i, off);
      zj2 += __shfl_xor(zj2, off);
    }
    if (lane == 0) {
      const float L = 1.4426950408889634f;
      const float sp = sig_par[m], so = sig_perp[m];
      const float nsp = -0.5f / fmaf(sp, sp, EPS_TOTAL);
      const float nso = -0.5f / fmaf(so, so, EPS_TOTAL);
      const float nsoL = nso * L;
      const float nspmoL = (nsp - nso) * L;
      const float t = nspmoL * dd2 + nsoL;
      float* o = mc_g + m * 8;
      o[0] = c1r;
      o[1] = c1i;
      o[2] = zj2;
      o[3] = dd2 * nsoL + log2f(alpha[m]);  // Km
      o[4] = dd2 * t;                        // A2
      o[5] = -2.f * t;                       // B2
      o[6] = nsoL;
      o[7] = nspmoL;
    }
  } else {  // ---- bsq ----
    const int w = threadIdx.x >> 6, lane = threadIdx.x & 63;
    const int b = (blockIdx.x - 768 - M_DIM / 4) * 4 + w;
    const int idx = b * N_DIM + lane;
    const float zr = z_re[idx], zi = z_im[idx];
    const float dr = d_re[idx], di = d_im[idx];
    float z2 = zr * zr + zi * zi;
    float dsq = dr * dr + di * di;
#pragma unroll
    for (int off = 1; off < 64; off <<= 1) {
      z2 += __shfl_xor(z2, off);
      dsq += __shfl_xor(dsq, off);
    }
    if (lane == 0) {
      bsq_g[b * 2] = z2;
      bsq_g[b * 2 + 1] = dsq;
    }
  }
}

// ------------- main: r15 structure verbatim (best measured: 42.5 us) -----
__global__ __launch_bounds__(256) void cpsf_mfma() {
  __shared__ __align__(16) unsigned short wbuf[8192];
  __shared__ __align__(16) unsigned short wgt_hi[64][68];

  const int tid = threadIdx.x;
  const int w = tid >> 6, lane = tid & 63;
  // XCD-aware swizzle over the full 1024-block grid.
  const int q = blockIdx.x >> 3, x = blockIdx.x & 7;
  const int ms = x + 8 * (q & 3);   // [0,32)
  const int bt = q >> 2;            // [0,32)
  const int b0 = bt * BTILE;
  const int g = lane >> 4;

  // ---- A fragments: prebuilt, coalesced lane*16B loads ----
  const int bw = bt * 4 + w;
  short8v A1h[4], A1l[4], A2h[4], A2l[4];
#pragma unroll
  for (int ks = 0; ks < 4; ++ks) {
    const unsigned short* ap =
        afrag_g + (((size_t)(bw * 4 + ks) * 4) * 64 + lane) * 8;
    A1h[ks] = *(const short8v*)(ap + 0 * 512);
    A1l[ks] = *(const short8v*)(ap + 1 * 512);
    A2h[ks] = *(const short8v*)(ap + 2 * 512);
    A2l[ks] = *(const short8v*)(ap + 3 * 512);
  }

  // per-b squared norms for this thread's 4 output rows (constant over m)
  float bz[4], bd[4];
#pragma unroll
  for (int r = 0; r < 4; ++r) {
    const int bloc = b0 + w * 16 + g * 4 + r;
    bz[r] = bsq_g[bloc * 2];
    bd[r] = bsq_g[bloc * 2 + 1];
  }

  const float2v TQ2[4] = {{0.019855071751231885f, 0.101666761293186630f},
                          {0.237233795041835510f, 0.408282678752175100f},
                          {0.591717321247824900f, 0.762766204958164500f},
                          {0.898333238706813370f, 0.980144928248768120f}};
  const float2v WQ2[4] = {{0.050614268145188130f, 0.111190517226687240f},
                          {0.156853322938943640f, 0.181341891689180990f},
                          {0.181341891689180990f, 0.156853322938943640f},
                          {0.111190517226687240f, 0.050614268145188130f}};

  float4v Tacc[4];
#pragma unroll
  for (int i = 0; i < 4; ++i) Tacc[i] = (float4v){0.f, 0.f, 0.f, 0.f};

#pragma unroll
  for (int ci = 0; ci < MR / 64; ++ci) {
    const int m0 = ms * MR + ci * 64;
    const int mtile0 = m0 >> 4;

#pragma unroll
    for (int mt = 0; mt < 4; ++mt) {
      // ---- stage this (ci,mt)'s wfrag chunk (16 KB) into LDS ----
      __syncthreads();  // all waves done reading wbuf from previous phase
      {
        const unsigned short* src =
            wfrag_g + ((size_t)((mtile0 + mt) * 4 + w)) * 2048 + lane * 8;
#pragma unroll
        for (int j = 0; j < 4; ++j)
          stage16(src + j * 512, &wbuf[(w * 4 + j) * 512]);
      }
      __syncthreads();  // staged data visible (vmcnt drained)

      // ---- K=128 GEMM from LDS ----
      // ipr, ipiP (z_im*dj_re), ipiN (z_re*dj_im), zd, ad
      float4v acc0 = {0.f, 0.f, 0.f, 0.f}, accP = acc0, accN = acc0,
              acc2 = acc0, acc3 = acc0;
#pragma unroll
      for (int ks = 0; ks < 4; ++ks) {
        const unsigned short* wp = &wbuf[(ks * 4) * 512 + lane * 8];
        const short8v w1h = *(const short8v*)(wp + 0 * 512);
        const short8v w1l = *(const short8v*)(wp + 1 * 512);
        const short8v w3h = *(const short8v*)(wp + 2 * 512);
        const short8v w3l = *(const short8v*)(wp + 3 * 512);
        const short8v a1h = A1h[ks], a1l = A1l[ks];
        // ipi trick: W2 = [-dj_im; dj_re] = k-slice-swapped W1 with one
        // half negated -> accumulate A1[ks^2] x W1[ks] into accP/accN.
        const short8v s1h = A1h[ks ^ 2], s1l = A1l[ks ^ 2];
        const short8v a2h = A2h[ks], a2l = A2l[ks];
        acc0 = MFMA(a1h, w1h, acc0);
        acc0 = MFMA(a1h, w1l, acc0);
        acc0 = MFMA(a1l, w1h, acc0);
        if (ks < 2) {
          accP = MFMA(s1h, w1h, accP);
          accP = MFMA(s1h, w1l, accP);
          accP = MFMA(s1l, w1h, accP);
        } else {
          accN = MFMA(s1h, w1h, accN);
          accN = MFMA(s1h, w1l, accN);
          accN = MFMA(s1l, w1h, accN);
        }
        acc2 = MFMA(a1h, w3h, acc2);
        acc2 = MFMA(a1h, w3l, acc2);
        acc2 = MFMA(a1l, w3h, acc2);
        acc3 = MFMA(a2h, w1h, acc3);
        acc3 = MFMA(a2h, w1l, acc3);
        acc3 = MFMA(a2l, w1h, acc3);
      }

      // poly quadrature: arg(t) = A2 t^2 + B2 t + C, exp2, alpha folded.
      const int mloc = mt * 16 + (lane & 15);
      const float4 mA = *(const float4*)(mc_g + (size_t)(m0 + mloc) * 8);
      const float4 mB = *(const float4*)(mc_g + (size_t)(m0 + mloc) * 8 + 4);
      const float c1r = mA.x, c1i = mA.y, zj2 = mA.z, Km = mA.w;
      const float A2 = mB.x, B2 = mB.y, nsoL = mB.z, nspmoL = mB.w;
#pragma unroll
      for (int r = 0; r < 4; ++r) {
        const float ipr2 = acc0[r] - c1r;
        const float ipi2 = (accP[r] - accN[r]) - c1i;
        const float q0 = fmaf(-2.f, acc2[r], bz[r]) + zj2;
        const float db = fmaf(fmaf(-2.f, acc3[r], bd[r]), nsoL, Km);
        const float r2 = fmaf(ipr2, ipr2, ipi2 * ipi2);
        const float bq = ipr2 * B2;
        const float cc = fmaf(nspmoL, r2, fmaf(nsoL, q0, db));
        const float2v A2v = {A2, A2}, bqv = {bq, bq}, ccv = {cc, cc};
        float2v qa = {0.f, 0.f};
#pragma unroll
        for (int kp = 0; kp < 4; ++kp) {
          const float2v tk = TQ2[kp];
          const float2v arg = (A2v * tk + bqv) * tk + ccv;
          const float2v ex = {fast_exp2(arg.x), fast_exp2(arg.y)};
          qa += WQ2[kp] * ex;
        }
        const int bloc = w * 16 + g * 4 + r;
        wgt_hi[bloc][mloc] = f32_bf16(qa.x + qa.y);
      }
    }

    // ---- That accumulation via MFMA (wgt single-bf16 x tfrag hi/lo);
    // wave-private wgt rows -> in-wave LDS ordering, no barrier ----
    const int mchunk = ms * (MR / 64) + ci;
#pragma unroll
    for (int ks2 = 0; ks2 < 2; ++ks2) {
      const int row = w * 16 + (lane & 15);
      const int colb = ks2 * 32 + g * 4;
      const short4v p0 = *(const short4v*)&wgt_hi[row][colb];
      const short4v p1 = *(const short4v*)&wgt_hi[row][colb + 16];
      const short8v ah = __builtin_shufflevector(p0, p1, 0, 1, 2, 3, 4, 5, 6, 7);
#pragma unroll
      for (int ct = 0; ct < 4; ++ct) {
        const size_t toff =
            ((((size_t)mchunk * 4 + ct) * 2 + ks2) * 2) * 512 + lane * 8;
        const short8v th = *(const short8v*)(tfrag_g + toff);
        const short8v tl = *(const short8v*)(tfrag_g + toff + 512);
        Tacc[ct] = MFMA(ah, th, Tacc[ct]);
        Tacc[ct] = MFMA(ah, tl, Tacc[ct]);
      }
    }
  }

  // partial T for this m-split: D row = 4g + r, col = ct*16+(lane&15).
#pragma unroll
  for (int ct = 0; ct < 4; ++ct)
#pragma unroll
    for (int r = 0; r < 4; ++r)
      part_g[((size_t)ms * B_DIM + (b0 + w * 16 + g * 4 + r)) * S_DIM +
             ct * 16 + (lane & 15)] = Tacc[ct][r];
}

// ------------- reduce partials (float4-vectorized) -----------------------
__global__ __launch_bounds__(256) void reduce_parts(float* __restrict__ out) {
  const int i = blockIdx.x * 256 + threadIdx.x;  // [0, 32768)
  float4 s = {0.f, 0.f, 0.f, 0.f};
#pragma unroll
  for (int p = 0; p < MSPLIT; ++p) {
    const float4 v = *(const float4*)(part_g + (size_t)p * B_DIM * S_DIM + i * 4);
    s.x += v.x;
    s.y += v.y;
    s.z += v.z;
    s.w += v.w;
  }
  *(float4*)(out + (size_t)i * 4) = s;
}

extern "C" void kernel_launch(void* const* d_in, const int* in_sizes, int n_in,
                              void* d_out, int out_size, void* d_ws,
                              size_t ws_size, hipStream_t stream) {
  const float* z_re = (const float*)d_in[0];
  const float* z_im = (const float*)d_in[1];
  const float* d_re = (const float*)d_in[2];
  const float* d_im = (const float*)d_in[3];
  const float* zj_re = (const float*)d_in[4];
  const float* zj_im = (const float*)d_in[5];
  const float* dj_re = (const float*)d_in[6];
  const float* dj_im = (const float*)d_in[7];
  const float* That_re = (const float*)d_in[8];
  const float* alpha = (const float*)d_in[10];
  const float* sig_par = (const float*)d_in[11];
  const float* sig_perp = (const float*)d_in[12];

  build_all<<<dim3(768 + M_DIM / 4 + B_DIM / 4), dim3(256), 0, stream>>>(
      zj_re, zj_im, dj_re, dj_im, That_re, alpha, sig_par, sig_perp, z_re,
      z_im, d_re, d_im);
  cpsf_mfma<<<dim3((B_DIM / BTILE) * MSPLIT), dim3(256), 0, stream>>>();
  reduce_parts<<<dim3(B_DIM * S_DIM / 1024), dim3(256), 0, stream>>>(
      (float*)d_out);
}